// Round 2
// baseline (1160.753 us; speedup 1.0000x reference)
//
#include <hip/hip_runtime.h>

// ---------------------------------------------------------------------------
// GAT encoder, 2 layers, MI355X — dtype-adaptive round.
// A probe kernel detects at runtime whether float inputs are f32 or bf16 and
// whether edge_index is int64 or int32 (flags stored in ws; all subsequent
// kernels branch wave-uniformly on them). Internal pipeline is all-f32 for
// precision; output store width follows the detected float dtype.
// Pipeline: probe -> memset counts -> hist -> scan -> scatter (CSR)
//   -> GEMM1 (x@W1 -> h1 f32) -> alpha1 -> node1 (online softmax -> hmid f32)
//   -> GEMM2 (hmid@W2 -> h2)  -> alpha2 -> node2 -> d_out
// ---------------------------------------------------------------------------

#define NNODES 50000
#define FIN 256
#define H1 4
#define CH 64

__device__ __forceinline__ float bf2f(ushort u) {
    union { unsigned int i; float f; } v; v.i = ((unsigned int)u) << 16; return v.f;
}
__device__ __forceinline__ ushort f2bf(float f) {
    union { float f; unsigned int i; } v; v.f = f;
    unsigned int r = v.i + 0x7fffu + ((v.i >> 16) & 1u);  // RNE
    return (ushort)(r >> 16);
}
// flag f: 1 = buffer holds f32, 0 = buffer holds bf16
__device__ __forceinline__ float load_in(const void* p, int i, int f) {
    return f ? ((const float*)p)[i] : bf2f(((const ushort*)p)[i]);
}
// flag f64: 1 = buffer holds int64, 0 = int32
__device__ __forceinline__ int load_idx(const void* p, long long i, int f64) {
    return f64 ? (int)((const long long*)p)[i] : ((const int*)p)[i];
}

// ---- dtype probe -----------------------------------------------------------
// bf16 data read as bf16: no non-finite values (inputs are casts of N(0,1)).
// f32 data read as bf16: even ushorts are random mantissa words -> exp field
// 0xFF with p=1/256 -> ~32 hits in 16384. Threshold 2 is >10 sigma safe.
// int64 indices (<2^31) read as int32: every odd word is 0. int32 indices:
// odd words are node ids, P(1024 odd words all zero) ~ 0.
__global__ __launch_bounds__(256) void probe_kernel(const ushort* __restrict__ x,
                                                    const int* __restrict__ ei,
                                                    int* __restrict__ flags) {
    __shared__ int s_nan, s_odd;
    if (threadIdx.x == 0) { s_nan = 0; s_odd = 0; }
    __syncthreads();
    int t = threadIdx.x, nanc = 0, oddc = 0;
    for (int i = t; i < 16384; i += 256) {
        ushort u = x[i];
        if (((u >> 7) & 0xFF) == 0xFF) nanc++;
    }
    for (int i = t; i < 2048; i += 256) {
        if (ei[2 * i + 1] != 0) oddc++;
    }
    if (nanc) atomicAdd(&s_nan, nanc);
    if (oddc) atomicAdd(&s_odd, oddc);
    __syncthreads();
    if (t == 0) {
        flags[0] = (s_nan >= 2) ? 1 : 0;  // 1 = floats are f32
        flags[1] = (s_odd == 0) ? 1 : 0;  // 1 = indices are int64
    }
}

// ---- CSR build -------------------------------------------------------------
__global__ void hist_kernel(const void* __restrict__ ei, int* __restrict__ counts,
                            int E, int Etot, int Nn, const int* __restrict__ flags) {
    int i = blockIdx.x * blockDim.x + threadIdx.x;
    if (i >= Etot) return;
    int f64 = flags[1];
    int dst = (i < E) ? load_idx(ei, (long long)E + i, f64) : (i - E);
    dst = min(max(dst, 0), Nn - 1);
    atomicAdd(&counts[dst], 1);
}

__global__ __launch_bounds__(1024) void scan_kernel(const int* __restrict__ counts,
                                                    int* __restrict__ offs,
                                                    int* __restrict__ cursor, int n) {
    __shared__ int part[1024];
    int tid = threadIdx.x;
    int chunk = (n + 1023) / 1024;
    int beg = tid * chunk, end = min(beg + chunk, n);
    int s = 0;
    for (int i = beg; i < end; ++i) s += counts[i];
    part[tid] = s;
    __syncthreads();
    for (int off = 1; off < 1024; off <<= 1) {
        int v = 0;
        if (tid >= off) v = part[tid - off];
        __syncthreads();
        part[tid] += v;
        __syncthreads();
    }
    int running = (tid == 0) ? 0 : part[tid - 1];  // exclusive prefix
    for (int i = beg; i < end; ++i) {
        offs[i] = running;
        cursor[i] = running;
        running += counts[i];
    }
    if (end >= n) offs[n] = part[1023];
}

__global__ void scatter_kernel(const void* __restrict__ ei, int* __restrict__ cursor,
                               int* __restrict__ csr_src, int E, int Etot, int Nn,
                               const int* __restrict__ flags) {
    int i = blockIdx.x * blockDim.x + threadIdx.x;
    if (i >= Etot) return;
    int f64 = flags[1];
    int src, dst;
    if (i < E) {
        src = load_idx(ei, i, f64);
        dst = load_idx(ei, (long long)E + i, f64);
    } else {
        src = dst = i - E;
    }
    src = min(max(src, 0), Nn - 1);
    dst = min(max(dst, 0), Nn - 1);
    int pos = atomicAdd(&cursor[dst], 1);
    csr_src[pos] = src;
}

// ---- f32 tiled GEMM: C[M,Nc] = A[M,K] @ B[K,Nc] ---------------------------
// block = 256 threads -> 64x64 output tile, 4x4 per-thread microtile, KB=16.
// A may be a raw input (dtype per flag) or an internal f32 buffer (a_raw=0).
// B is always a raw input (dtype per flag).
__global__ __launch_bounds__(256) void gemm_f32(const void* __restrict__ A,
                                                const void* __restrict__ B,
                                                float* __restrict__ C,
                                                int M, int K, int Nc,
                                                const int* __restrict__ flags,
                                                int a_raw) {
    __shared__ float As[16][65];  // [k][row], padded
    __shared__ float Bs[16][64];  // [k][col]
    int f = flags[0];
    int t = threadIdx.x;
    int ty = t >> 4, tx = t & 15;
    int row0 = blockIdx.x * 64, col0 = blockIdx.y * 64;
    float acc[4][4] = {};
    for (int kb = 0; kb < K; kb += 16) {
#pragma unroll
        for (int l = 0; l < 4; ++l) {
            int idx = t + l * 256;          // 0..1023
            int r = idx >> 4, kk = idx & 15;
            int grow = min(row0 + r, M - 1);
            int gi = grow * K + kb + kk;
            float v;
            if (a_raw) v = load_in(A, gi, f);
            else       v = ((const float*)A)[gi];
            As[kk][r] = v;
        }
#pragma unroll
        for (int l = 0; l < 4; ++l) {
            int idx = t + l * 256;
            int kk = idx >> 6, c = idx & 63;
            int gi = (kb + kk) * Nc + col0 + c;
            Bs[kk][c] = load_in(B, gi, f);
        }
        __syncthreads();
#pragma unroll
        for (int kk = 0; kk < 16; ++kk) {
            float av[4], bv[4];
#pragma unroll
            for (int i = 0; i < 4; ++i) av[i] = As[kk][ty * 4 + i];
#pragma unroll
            for (int j = 0; j < 4; ++j) bv[j] = Bs[kk][tx * 4 + j];
#pragma unroll
            for (int i = 0; i < 4; ++i)
#pragma unroll
                for (int j = 0; j < 4; ++j) acc[i][j] += av[i] * bv[j];
        }
        __syncthreads();
    }
#pragma unroll
    for (int i = 0; i < 4; ++i) {
        int row = row0 + ty * 4 + i;
        if (row < M) {
#pragma unroll
            for (int j = 0; j < 4; ++j)
                C[(size_t)row * Nc + col0 + tx * 4 + j] = acc[i][j];
        }
    }
}

// ---- attention logits: alpha[n,h] = sum_c h[n,h,c] * att[h,c] --------------
__global__ __launch_bounds__(256) void alpha_kernel(const float* __restrict__ h,
                                                    const void* __restrict__ a_s,
                                                    const void* __restrict__ a_d,
                                                    float* __restrict__ out_s,
                                                    float* __restrict__ out_d,
                                                    int Nn, int H,
                                                    const int* __restrict__ flags) {
    int f = flags[0];
    int wave = threadIdx.x >> 6, lane = threadIdx.x & 63;
    int n = blockIdx.x * 4 + wave;
    if (n >= Nn) return;
    for (int hh = 0; hh < H; ++hh) {
        float v = h[(size_t)n * H * 64 + hh * 64 + lane];
        float ps = v * load_in(a_s, hh * 64 + lane, f);
        float pd = v * load_in(a_d, hh * 64 + lane, f);
#pragma unroll
        for (int off = 32; off > 0; off >>= 1) {
            ps += __shfl_down(ps, off);
            pd += __shfl_down(pd, off);
        }
        if (lane == 0) {
            out_s[n * H + hh] = ps;
            out_d[n * H + hh] = pd;
        }
    }
}

// ---- layer-1 aggregation: block per dst node, wave = head, lane = channel --
__global__ __launch_bounds__(256) void gat_node1(const int* __restrict__ csr_src,
                                                 const int* __restrict__ offs,
                                                 const float* __restrict__ asrc,
                                                 const float* __restrict__ adst,
                                                 const float* __restrict__ h1,
                                                 const void* __restrict__ b1,
                                                 float* __restrict__ hmid,
                                                 int Nn, const int* __restrict__ flags) {
    int f = flags[0];
    int nid = blockIdx.x;
    int hh = threadIdx.x >> 6, c = threadIdx.x & 63;
    int beg = offs[nid], end = offs[nid + 1];
    float ad = adst[nid * H1 + hh];
    float m = -INFINITY, l = 0.f, acc = 0.f;
    for (int e = beg; e < end; ++e) {
        int src = csr_src[e];
        src = min(max(src, 0), Nn - 1);
        float s = asrc[src * H1 + hh] + ad;
        s = s > 0.f ? s : 0.2f * s;            // leaky_relu 0.2
        float mn = fmaxf(m, s);
        float sc = __expf(m - mn);
        float p = __expf(s - mn);
        float v = h1[(size_t)src * FIN + hh * 64 + c];
        l = l * sc + p;
        acc = acc * sc + p * v;
        m = mn;
    }
    float o = acc / (l + 1e-16f) + load_in(b1, hh * 64 + c, f);
    o = o > 0.f ? o : __expf(o) - 1.f;         // ELU
    hmid[(size_t)nid * FIN + hh * 64 + c] = o;
}

// ---- layer-2 aggregation: wave per dst node (H=1), lane = channel ----------
__global__ __launch_bounds__(256) void gat_node2(const int* __restrict__ csr_src,
                                                 const int* __restrict__ offs,
                                                 const float* __restrict__ asrc,
                                                 const float* __restrict__ adst,
                                                 const float* __restrict__ h2,
                                                 const void* __restrict__ b2,
                                                 void* __restrict__ out, int Nn,
                                                 const int* __restrict__ flags) {
    int f = flags[0];
    int wave = threadIdx.x >> 6, lane = threadIdx.x & 63;
    int n = blockIdx.x * 4 + wave;
    if (n >= Nn) return;
    int beg = offs[n], end = offs[n + 1];
    float ad = adst[n];
    float m = -INFINITY, l = 0.f, acc = 0.f;
    for (int e = beg; e < end; ++e) {
        int src = csr_src[e];
        src = min(max(src, 0), Nn - 1);
        float s = asrc[src] + ad;
        s = s > 0.f ? s : 0.2f * s;
        float mn = fmaxf(m, s);
        float sc = __expf(m - mn);
        float p = __expf(s - mn);
        float v = h2[(size_t)src * CH + lane];
        l = l * sc + p;
        acc = acc * sc + p * v;
        m = mn;
    }
    float o = acc / (l + 1e-16f) + load_in(b2, lane, f);
    size_t oi = (size_t)n * CH + lane;
    if (f) ((float*)out)[oi] = o;
    else   ((ushort*)out)[oi] = f2bf(o);
}

extern "C" void kernel_launch(void* const* d_in, const int* in_sizes, int n_in,
                              void* d_out, int out_size, void* d_ws, size_t ws_size,
                              hipStream_t stream) {
    const void* x   = d_in[0];
    const void* ei  = d_in[1];
    const void* W1  = d_in[2];
    const void* as1 = d_in[3];
    const void* ad1 = d_in[4];
    const void* b1  = d_in[5];
    const void* W2  = d_in[6];
    const void* as2 = d_in[7];
    const void* ad2 = d_in[8];
    const void* b2  = d_in[9];

    const int Nn = in_sizes[0] / FIN;      // 50000
    const int E  = in_sizes[1] / 2;        // 1600000
    const int ET = E + Nn;

    // workspace carve-up (256B aligned), ~125 MB total
    char* ws = (char*)d_ws;
    size_t off = 0;
    auto alloc = [&](size_t bytes) {
        size_t o = off;
        off += (bytes + 255) & ~(size_t)255;
        return o;
    };
    float* h1     = (float*)(ws + alloc((size_t)Nn * FIN * 4));
    float* hmid   = (float*)(ws + alloc((size_t)Nn * FIN * 4));
    float* h2     = (float*)(ws + alloc((size_t)Nn * CH * 4));
    float* as1f   = (float*)(ws + alloc((size_t)Nn * H1 * 4));
    float* ad1f   = (float*)(ws + alloc((size_t)Nn * H1 * 4));
    float* as2f   = (float*)(ws + alloc((size_t)Nn * 4));
    float* ad2f   = (float*)(ws + alloc((size_t)Nn * 4));
    int*   counts = (int*)(ws + alloc((size_t)Nn * 4));
    int*   offs   = (int*)(ws + alloc((size_t)(Nn + 1) * 4));
    int*   cursor = (int*)(ws + alloc((size_t)Nn * 4));
    int*   csr    = (int*)(ws + alloc((size_t)ET * 4));
    int*   flags  = (int*)(ws + alloc(256));
    (void)ws_size; (void)n_in; (void)out_size;

    probe_kernel<<<1, 256, 0, stream>>>((const ushort*)x, (const int*)ei, flags);

    hipMemsetAsync(counts, 0, (size_t)Nn * 4, stream);
    int eb = (ET + 255) / 256;
    hist_kernel<<<eb, 256, 0, stream>>>(ei, counts, E, ET, Nn, flags);
    scan_kernel<<<1, 1024, 0, stream>>>(counts, offs, cursor, Nn);
    scatter_kernel<<<eb, 256, 0, stream>>>(ei, cursor, csr, E, ET, Nn, flags);

    // layer 1
    gemm_f32<<<dim3((Nn + 63) / 64, FIN / 64), 256, 0, stream>>>(
        x, W1, h1, Nn, FIN, FIN, flags, 1);
    alpha_kernel<<<(Nn + 3) / 4, 256, 0, stream>>>(h1, as1, ad1, as1f, ad1f, Nn, H1, flags);
    gat_node1<<<Nn, 256, 0, stream>>>(csr, offs, as1f, ad1f, h1, b1, hmid, Nn, flags);

    // layer 2
    gemm_f32<<<dim3((Nn + 63) / 64, CH / 64), 256, 0, stream>>>(
        hmid, W2, h2, Nn, FIN, CH, flags, 0);
    alpha_kernel<<<(Nn + 3) / 4, 256, 0, stream>>>(h2, as2, ad2, as2f, ad2f, Nn, 1, flags);
    gat_node2<<<(Nn + 3) / 4, 256, 0, stream>>>(csr, offs, as2f, ad2f, h2, b2, d_out, Nn, flags);
}

// Round 3
// 872.072 us; speedup vs baseline: 1.3310x; 1.3310x over previous
//
#include <hip/hip_runtime.h>

// ---------------------------------------------------------------------------
// GAT encoder, 2 layers, MI355X — round 3.
// Dtype-adaptive (probe detects f32-vs-bf16 floats, i64-vs-i32 indices).
// Internal tensors bf16 (halves gather traffic), f32 accumulation everywhere.
// Direct-sum softmax (no max subtraction — logits bounded, exp can't overflow)
// removes the serial online-rescale chain. One wave per node in aggregation.
// MFMA bf16 GEMMs.
// ---------------------------------------------------------------------------

typedef __attribute__((ext_vector_type(8))) short short8;
typedef __attribute__((ext_vector_type(4))) float floatx4;

#define FIN 256
#define H1 4
#define CH 64

__device__ __forceinline__ float bf2f(ushort u) {
    union { unsigned int i; float f; } v; v.i = ((unsigned int)u) << 16; return v.f;
}
__device__ __forceinline__ ushort f2bf(float f) {
    union { float f; unsigned int i; } v; v.f = f;
    unsigned int r = v.i + 0x7fffu + ((v.i >> 16) & 1u);  // RNE
    return (ushort)(r >> 16);
}
__device__ __forceinline__ float load_in(const void* p, int i, int f) {
    return f ? ((const float*)p)[i] : bf2f(((const ushort*)p)[i]);
}
__device__ __forceinline__ int load_idx(const void* p, long long i, int f64) {
    return f64 ? (int)((const long long*)p)[i] : ((const int*)p)[i];
}

// ---- dtype probe (see round-1 notes; discriminators are >10 sigma) ---------
__global__ __launch_bounds__(256) void probe_kernel(const ushort* __restrict__ x,
                                                    const int* __restrict__ ei,
                                                    int* __restrict__ flags) {
    __shared__ int s_nan, s_odd;
    if (threadIdx.x == 0) { s_nan = 0; s_odd = 0; }
    __syncthreads();
    int t = threadIdx.x, nanc = 0, oddc = 0;
    for (int i = t; i < 16384; i += 256) {
        ushort u = x[i];
        if (((u >> 7) & 0xFF) == 0xFF) nanc++;
    }
    for (int i = t; i < 2048; i += 256)
        if (ei[2 * i + 1] != 0) oddc++;
    if (nanc) atomicAdd(&s_nan, nanc);
    if (oddc) atomicAdd(&s_odd, oddc);
    __syncthreads();
    if (t == 0) {
        flags[0] = (s_nan >= 2) ? 1 : 0;  // 1 = floats are f32
        flags[1] = (s_odd == 0) ? 1 : 0;  // 1 = indices are int64
    }
}

// ---- conversions -----------------------------------------------------------
__global__ void convert_kernel(const void* __restrict__ in, ushort* __restrict__ out,
                               int n, const int* __restrict__ flags) {
    int i = blockIdx.x * blockDim.x + threadIdx.x;
    if (i < n) out[i] = f2bf(load_in(in, i, flags[0]));
}

// out[n*K + k] = in[k*Nc + n], bf16 out
__global__ void transpose_kernel(const void* __restrict__ in, ushort* __restrict__ out,
                                 int K, int Nc, const int* __restrict__ flags) {
    int i = blockIdx.x * blockDim.x + threadIdx.x;
    if (i >= K * Nc) return;
    int n = i / K, k = i % K;
    out[i] = f2bf(load_in(in, k * Nc + n, flags[0]));
}

// ---- CSR build -------------------------------------------------------------
__global__ void hist_kernel(const void* __restrict__ ei, int* __restrict__ counts,
                            int E, int Etot, int Nn, const int* __restrict__ flags) {
    int i = blockIdx.x * blockDim.x + threadIdx.x;
    if (i >= Etot) return;
    int dst = (i < E) ? load_idx(ei, (long long)E + i, flags[1]) : (i - E);
    dst = min(max(dst, 0), Nn - 1);
    atomicAdd(&counts[dst], 1);
}

__global__ __launch_bounds__(1024) void scan_kernel(const int* __restrict__ counts,
                                                    int* __restrict__ offs,
                                                    int* __restrict__ cursor, int n) {
    __shared__ int part[1024];
    int tid = threadIdx.x;
    int chunk = (n + 1023) / 1024;
    int beg = tid * chunk, end = min(beg + chunk, n);
    int s = 0;
    for (int i = beg; i < end; ++i) s += counts[i];
    part[tid] = s;
    __syncthreads();
    for (int off = 1; off < 1024; off <<= 1) {
        int v = 0;
        if (tid >= off) v = part[tid - off];
        __syncthreads();
        part[tid] += v;
        __syncthreads();
    }
    int running = (tid == 0) ? 0 : part[tid - 1];  // exclusive prefix
    for (int i = beg; i < end; ++i) {
        offs[i] = running;
        cursor[i] = running;
        running += counts[i];
    }
    if (end >= n) offs[n] = part[1023];
}

__global__ void scatter_kernel(const void* __restrict__ ei, int* __restrict__ cursor,
                               int* __restrict__ csr_src, int E, int Etot, int Nn,
                               const int* __restrict__ flags) {
    int i = blockIdx.x * blockDim.x + threadIdx.x;
    if (i >= Etot) return;
    int f64 = flags[1];
    int src, dst;
    if (i < E) {
        src = load_idx(ei, i, f64);
        dst = load_idx(ei, (long long)E + i, f64);
    } else {
        src = dst = i - E;
    }
    src = min(max(src, 0), Nn - 1);
    dst = min(max(dst, 0), Nn - 1);
    int pos = atomicAdd(&cursor[dst], 1);
    csr_src[pos] = src;
}

// ---- MFMA bf16 GEMM: C[M,Nc] = A[M,K] @ Bt[Nc,K]^T, bf16 out ---------------
// 4 waves/block; wave w: rows [bx*256+w*64,+64), cols [by*64,+64).
__global__ __launch_bounds__(256) void gemm_bf16(const ushort* __restrict__ A,
                                                 const ushort* __restrict__ Bt,
                                                 ushort* __restrict__ C,
                                                 int M, int K, int Nc) {
    int tid = threadIdx.x;
    int wave = tid >> 6, lane = tid & 63, quad = lane >> 4, l16 = lane & 15;
    int rbase = blockIdx.x * 256 + wave * 64;
    int cbase = blockIdx.y * 64;
    floatx4 acc[4][4];
#pragma unroll
    for (int i = 0; i < 4; i++)
#pragma unroll
        for (int j = 0; j < 4; j++) acc[i][j] = (floatx4)0.f;

    for (int kb = 0; kb < K; kb += 32) {
        int k0 = kb + quad * 8;
        short8 a[4], b[4];
#pragma unroll
        for (int mt = 0; mt < 4; mt++) {
            int row = rbase + mt * 16 + l16;
            if (row >= M) row = M - 1;  // clamp; oob rows never stored
            a[mt] = *reinterpret_cast<const short8*>(A + (size_t)row * K + k0);
        }
#pragma unroll
        for (int nt = 0; nt < 4; nt++) {
            int col = cbase + nt * 16 + l16;
            b[nt] = *reinterpret_cast<const short8*>(Bt + (size_t)col * K + k0);
        }
#pragma unroll
        for (int mt = 0; mt < 4; mt++)
#pragma unroll
            for (int nt = 0; nt < 4; nt++)
                acc[mt][nt] = __builtin_amdgcn_mfma_f32_16x16x32_bf16(
                    a[mt], b[nt], acc[mt][nt], 0, 0, 0);
    }
    // C/D layout: col = lane&15, row = quad*4 + reg   [m89-verified]
#pragma unroll
    for (int mt = 0; mt < 4; mt++) {
#pragma unroll
        for (int r = 0; r < 4; r++) {
            int row = rbase + mt * 16 + quad * 4 + r;
            if (row < M) {
#pragma unroll
                for (int nt = 0; nt < 4; nt++) {
                    int col = cbase + nt * 16 + l16;
                    C[(size_t)row * Nc + col] = f2bf(acc[mt][nt][r]);
                }
            }
        }
    }
}

// ---- attention logits, H=4: wave per node, lane = 4 channels ---------------
__global__ __launch_bounds__(256) void alpha4_kernel(const ushort* __restrict__ h,
                                                     const void* __restrict__ a_s,
                                                     const void* __restrict__ a_d,
                                                     float* __restrict__ out_s,
                                                     float* __restrict__ out_d,
                                                     int Nn, const int* __restrict__ flags) {
    int f = flags[0];
    int wave = threadIdx.x >> 6, lane = threadIdx.x & 63;
    int n = blockIdx.x * 4 + wave;
    if (n >= Nn) return;
    uint2 vv = *reinterpret_cast<const uint2*>(h + (size_t)n * 256 + lane * 4);
    union { unsigned int i; float fl; } c0, c1, c2, c3;
    c0.i = vv.x << 16; c1.i = vv.x & 0xffff0000u;
    c2.i = vv.y << 16; c3.i = vv.y & 0xffff0000u;
    float ps = c0.fl * load_in(a_s, lane * 4 + 0, f) + c1.fl * load_in(a_s, lane * 4 + 1, f)
             + c2.fl * load_in(a_s, lane * 4 + 2, f) + c3.fl * load_in(a_s, lane * 4 + 3, f);
    float pd = c0.fl * load_in(a_d, lane * 4 + 0, f) + c1.fl * load_in(a_d, lane * 4 + 1, f)
             + c2.fl * load_in(a_d, lane * 4 + 2, f) + c3.fl * load_in(a_d, lane * 4 + 3, f);
#pragma unroll
    for (int off = 8; off > 0; off >>= 1) {   // reduce within 16-lane head group
        ps += __shfl_down(ps, off, 16);
        pd += __shfl_down(pd, off, 16);
    }
    if ((lane & 15) == 0) {
        out_s[n * H1 + (lane >> 4)] = ps;
        out_d[n * H1 + (lane >> 4)] = pd;
    }
}

// ---- attention logits, H=1: wave per node, lane = channel ------------------
__global__ __launch_bounds__(256) void alpha1_kernel(const ushort* __restrict__ h,
                                                     const void* __restrict__ a_s,
                                                     const void* __restrict__ a_d,
                                                     float* __restrict__ out_s,
                                                     float* __restrict__ out_d,
                                                     int Nn, const int* __restrict__ flags) {
    int f = flags[0];
    int wave = threadIdx.x >> 6, lane = threadIdx.x & 63;
    int n = blockIdx.x * 4 + wave;
    if (n >= Nn) return;
    float v = bf2f(h[(size_t)n * CH + lane]);
    float ps = v * load_in(a_s, lane, f);
    float pd = v * load_in(a_d, lane, f);
#pragma unroll
    for (int off = 32; off > 0; off >>= 1) {
        ps += __shfl_down(ps, off);
        pd += __shfl_down(pd, off);
    }
    if (lane == 0) { out_s[n] = ps; out_d[n] = pd; }
}

// ---- layer-1 aggregation: ONE wave per node; lane = head(lane>>4) x 4 ch ---
// Direct-sum softmax: p = exp(leaky(s)); acc += p*v; l += p.  (|s| <~ 12)
__global__ __launch_bounds__(256) void gat_node1(const int* __restrict__ csr_src,
                                                 const int* __restrict__ offs,
                                                 const float* __restrict__ asrc,
                                                 const float* __restrict__ adst,
                                                 const ushort* __restrict__ h1b,
                                                 const void* __restrict__ b1,
                                                 ushort* __restrict__ hmidb,
                                                 int Nn, const int* __restrict__ flags) {
    int f = flags[0];
    int wave = threadIdx.x >> 6, lane = threadIdx.x & 63;
    int n = blockIdx.x * 4 + wave;
    if (n >= Nn) return;
    int hh = lane >> 4;
    float ad = adst[n * H1 + hh];
    int beg = offs[n], end = offs[n + 1];   // end > beg (self-loop guaranteed)
    float acc0 = 0.f, acc1 = 0.f, acc2 = 0.f, acc3 = 0.f, l = 0.f;

    int src = csr_src[beg];
    float a = asrc[src * H1 + hh];
    uint2 vv = *reinterpret_cast<const uint2*>(h1b + (size_t)src * FIN + lane * 4);
    for (int e = beg;;) {
        int nxt = e + 1;
        bool more = nxt < end;
        int srcn = 0; float an = 0.f; uint2 vvn = {0, 0};
        if (more) {  // prefetch next edge while computing current
            srcn = csr_src[nxt];
            an = asrc[srcn * H1 + hh];
            vvn = *reinterpret_cast<const uint2*>(h1b + (size_t)srcn * FIN + lane * 4);
        }
        float s = a + ad;
        s = s > 0.f ? s : 0.2f * s;          // leaky_relu 0.2
        float p = __expf(s);
        l += p;
        union { unsigned int i; float fl; } c0, c1, c2, c3;
        c0.i = vv.x << 16; c1.i = vv.x & 0xffff0000u;
        c2.i = vv.y << 16; c3.i = vv.y & 0xffff0000u;
        acc0 += p * c0.fl; acc1 += p * c1.fl;
        acc2 += p * c2.fl; acc3 += p * c3.fl;
        if (!more) break;
        e = nxt; src = srcn; a = an; vv = vvn;
    }
    float inv = 1.f / (l + 1e-16f);
    float o0 = acc0 * inv + load_in(b1, lane * 4 + 0, f);
    float o1 = acc1 * inv + load_in(b1, lane * 4 + 1, f);
    float o2 = acc2 * inv + load_in(b1, lane * 4 + 2, f);
    float o3 = acc3 * inv + load_in(b1, lane * 4 + 3, f);
    o0 = o0 > 0.f ? o0 : __expf(o0) - 1.f;   // ELU
    o1 = o1 > 0.f ? o1 : __expf(o1) - 1.f;
    o2 = o2 > 0.f ? o2 : __expf(o2) - 1.f;
    o3 = o3 > 0.f ? o3 : __expf(o3) - 1.f;
    ushort4 st;
    st.x = f2bf(o0); st.y = f2bf(o1); st.z = f2bf(o2); st.w = f2bf(o3);
    *reinterpret_cast<ushort4*>(hmidb + (size_t)n * FIN + lane * 4) = st;
}

// ---- layer-2 aggregation: one wave per node (H=1), lane = channel ----------
__global__ __launch_bounds__(256) void gat_node2(const int* __restrict__ csr_src,
                                                 const int* __restrict__ offs,
                                                 const float* __restrict__ asrc,
                                                 const float* __restrict__ adst,
                                                 const ushort* __restrict__ h2b,
                                                 const void* __restrict__ b2,
                                                 void* __restrict__ out, int Nn,
                                                 const int* __restrict__ flags) {
    int f = flags[0];
    int wave = threadIdx.x >> 6, lane = threadIdx.x & 63;
    int n = blockIdx.x * 4 + wave;
    if (n >= Nn) return;
    float ad = adst[n];
    int beg = offs[n], end = offs[n + 1];
    float acc = 0.f, l = 0.f;

    int src = csr_src[beg];
    float a = asrc[src];
    ushort v = h2b[(size_t)src * CH + lane];
    for (int e = beg;;) {
        int nxt = e + 1;
        bool more = nxt < end;
        int srcn = 0; float an = 0.f; ushort vn = 0;
        if (more) {
            srcn = csr_src[nxt];
            an = asrc[srcn];
            vn = h2b[(size_t)srcn * CH + lane];
        }
        float s = a + ad;
        s = s > 0.f ? s : 0.2f * s;
        float p = __expf(s);
        l += p;
        acc += p * bf2f(v);
        if (!more) break;
        e = nxt; src = srcn; a = an; v = vn;
    }
    float o = acc / (l + 1e-16f) + load_in(b2, lane, f);
    size_t oi = (size_t)n * CH + lane;
    if (f) ((float*)out)[oi] = o;
    else   ((ushort*)out)[oi] = f2bf(o);
}

extern "C" void kernel_launch(void* const* d_in, const int* in_sizes, int n_in,
                              void* d_out, int out_size, void* d_ws, size_t ws_size,
                              hipStream_t stream) {
    const void* x   = d_in[0];
    const void* ei  = d_in[1];
    const void* W1  = d_in[2];
    const void* as1 = d_in[3];
    const void* ad1 = d_in[4];
    const void* b1  = d_in[5];
    const void* W2  = d_in[6];
    const void* as2 = d_in[7];
    const void* ad2 = d_in[8];
    const void* b2  = d_in[9];

    const int Nn = in_sizes[0] / FIN;      // 50000
    const int E  = in_sizes[1] / 2;        // 1600000
    const int ET = E + Nn;

    char* ws = (char*)d_ws;
    size_t off = 0;
    auto alloc = [&](size_t bytes) {
        size_t o = off;
        off += (bytes + 255) & ~(size_t)255;
        return o;
    };
    ushort* xb    = (ushort*)(ws + alloc((size_t)Nn * FIN * 2));
    ushort* h1b   = (ushort*)(ws + alloc((size_t)Nn * FIN * 2));
    ushort* hmidb = (ushort*)(ws + alloc((size_t)Nn * FIN * 2));
    ushort* h2b   = (ushort*)(ws + alloc((size_t)Nn * CH * 2));
    ushort* Wt1   = (ushort*)(ws + alloc((size_t)FIN * FIN * 2));
    ushort* Wt2   = (ushort*)(ws + alloc((size_t)CH * FIN * 2));
    float* as1f   = (float*)(ws + alloc((size_t)Nn * H1 * 4));
    float* ad1f   = (float*)(ws + alloc((size_t)Nn * H1 * 4));
    float* as2f   = (float*)(ws + alloc((size_t)Nn * 4));
    float* ad2f   = (float*)(ws + alloc((size_t)Nn * 4));
    int*   counts = (int*)(ws + alloc((size_t)Nn * 4));
    int*   offs   = (int*)(ws + alloc((size_t)(Nn + 1) * 4));
    int*   cursor = (int*)(ws + alloc((size_t)Nn * 4));
    int*   csr    = (int*)(ws + alloc((size_t)ET * 4));
    int*   flags  = (int*)(ws + alloc(256));
    (void)ws_size; (void)n_in; (void)out_size;

    probe_kernel<<<1, 256, 0, stream>>>((const ushort*)x, (const int*)ei, flags);
    hipMemsetAsync(counts, 0, (size_t)Nn * 4, stream);

    // conversions (depend only on probe)
    convert_kernel<<<(Nn * FIN + 255) / 256, 256, 0, stream>>>(x, xb, Nn * FIN, flags);
    transpose_kernel<<<(FIN * FIN + 255) / 256, 256, 0, stream>>>(W1, Wt1, FIN, FIN, flags);
    transpose_kernel<<<(FIN * CH + 255) / 256, 256, 0, stream>>>(W2, Wt2, FIN, CH, flags);

    // CSR
    int eb = (ET + 255) / 256;
    hist_kernel<<<eb, 256, 0, stream>>>(ei, counts, E, ET, Nn, flags);
    scan_kernel<<<1, 1024, 0, stream>>>(counts, offs, cursor, Nn);
    scatter_kernel<<<eb, 256, 0, stream>>>(ei, cursor, csr, E, ET, Nn, flags);

    // layer 1
    gemm_bf16<<<dim3((Nn + 255) / 256, FIN / 64), 256, 0, stream>>>(xb, Wt1, h1b, Nn, FIN, FIN);
    alpha4_kernel<<<(Nn + 3) / 4, 256, 0, stream>>>(h1b, as1, ad1, as1f, ad1f, Nn, flags);
    gat_node1<<<(Nn + 3) / 4, 256, 0, stream>>>(csr, offs, as1f, ad1f, h1b, b1, hmidb, Nn, flags);

    // layer 2
    gemm_bf16<<<dim3((Nn + 255) / 256, CH / 64), 256, 0, stream>>>(hmidb, Wt2, h2b, Nn, FIN, CH);
    alpha1_kernel<<<(Nn + 3) / 4, 256, 0, stream>>>(h2b, as2, ad2, as2f, ad2f, Nn, flags);
    gat_node2<<<(Nn + 3) / 4, 256, 0, stream>>>(csr, offs, as2f, ad2f, h2b, b2, d_out, Nn, flags);
}

// Round 4
// 674.997 us; speedup vs baseline: 1.7196x; 1.2920x over previous
//
#include <hip/hip_runtime.h>

// ---------------------------------------------------------------------------
// GAT encoder, 2 layers, MI355X — round 4.
// Dtype-adaptive (probe: f32-vs-bf16 floats, i64-vs-i32 indices).
// bf16 internal tensors, f32 accumulation. Direct-sum softmax (logits bounded).
// Aggregation: 1 wave/node, 8-deep chunked gather pipeline (MLP=8).
// Alpha logits fused into MFMA GEMM epilogue (in-wave 16-lane reduction).
// 10 dispatches: probe, memset, prep, hist, scan, scatter, gemm1, node1,
//                gemm2, node2.
// ---------------------------------------------------------------------------

typedef __attribute__((ext_vector_type(8))) short short8;
typedef __attribute__((ext_vector_type(4))) float floatx4;

#define FIN 256
#define H1 4
#define CH 64

__device__ __forceinline__ float bf2f(ushort u) {
    union { unsigned int i; float f; } v; v.i = ((unsigned int)u) << 16; return v.f;
}
__device__ __forceinline__ ushort f2bf(float f) {
    union { float f; unsigned int i; } v; v.f = f;
    unsigned int r = v.i + 0x7fffu + ((v.i >> 16) & 1u);  // RNE
    return (ushort)(r >> 16);
}
__device__ __forceinline__ float load_in(const void* p, int i, int f) {
    return f ? ((const float*)p)[i] : bf2f(((const ushort*)p)[i]);
}
__device__ __forceinline__ int load_idx(const void* p, long long i, int f64) {
    return f64 ? (int)((const long long*)p)[i] : ((const int*)p)[i];
}

// ---- dtype probe (discriminators >10 sigma; see round-1 notes) -------------
__global__ __launch_bounds__(256) void probe_kernel(const ushort* __restrict__ x,
                                                    const int* __restrict__ ei,
                                                    int* __restrict__ flags) {
    __shared__ int s_nan, s_odd;
    if (threadIdx.x == 0) { s_nan = 0; s_odd = 0; }
    __syncthreads();
    int t = threadIdx.x, nanc = 0, oddc = 0;
    for (int i = t; i < 16384; i += 256) {
        ushort u = x[i];
        if (((u >> 7) & 0xFF) == 0xFF) nanc++;
    }
    for (int i = t; i < 2048; i += 256)
        if (ei[2 * i + 1] != 0) oddc++;
    if (nanc) atomicAdd(&s_nan, nanc);
    if (oddc) atomicAdd(&s_odd, oddc);
    __syncthreads();
    if (t == 0) {
        flags[0] = (s_nan >= 2) ? 1 : 0;  // 1 = floats are f32
        flags[1] = (s_odd == 0) ? 1 : 0;  // 1 = indices are int64
    }
}

// ---- prep: convert x -> bf16, build W1^T, W2^T (one dispatch) --------------
__global__ void prep_kernel(const void* __restrict__ x, const void* __restrict__ W1,
                            const void* __restrict__ W2, ushort* __restrict__ xb,
                            ushort* __restrict__ Wt1, ushort* __restrict__ Wt2,
                            int NC, const int* __restrict__ flags) {
    int f = flags[0];
    int i = blockIdx.x * blockDim.x + threadIdx.x;
    if (i < NC) { xb[i] = f2bf(load_in(x, i, f)); return; }
    int j = i - NC;
    if (j < FIN * FIN) {  // Wt1[n*256+k] = W1[k*256+n]
        int n = j / FIN, k = j % FIN;
        Wt1[j] = f2bf(load_in(W1, k * FIN + n, f));
        return;
    }
    j -= FIN * FIN;
    if (j < CH * FIN) {   // Wt2[n*256+k] = W2[k*64+n]
        int n = j / FIN, k = j % FIN;
        Wt2[j] = f2bf(load_in(W2, k * CH + n, f));
    }
}

// ---- CSR build -------------------------------------------------------------
__global__ void hist_kernel(const void* __restrict__ ei, int* __restrict__ counts,
                            int E, int Etot, int Nn, const int* __restrict__ flags) {
    int i = blockIdx.x * blockDim.x + threadIdx.x;
    if (i >= Etot) return;
    int dst = (i < E) ? load_idx(ei, (long long)E + i, flags[1]) : (i - E);
    dst = min(max(dst, 0), Nn - 1);
    atomicAdd(&counts[dst], 1);
}

__global__ __launch_bounds__(1024) void scan_kernel(const int* __restrict__ counts,
                                                    int* __restrict__ offs,
                                                    int* __restrict__ cursor, int n) {
    __shared__ int part[1024];
    int tid = threadIdx.x;
    int chunk = (n + 1023) / 1024;
    int beg = tid * chunk, end = min(beg + chunk, n);
    int s = 0;
    for (int i = beg; i < end; ++i) s += counts[i];
    part[tid] = s;
    __syncthreads();
    for (int off = 1; off < 1024; off <<= 1) {
        int v = 0;
        if (tid >= off) v = part[tid - off];
        __syncthreads();
        part[tid] += v;
        __syncthreads();
    }
    int running = (tid == 0) ? 0 : part[tid - 1];  // exclusive prefix
    for (int i = beg; i < end; ++i) {
        offs[i] = running;
        cursor[i] = running;
        running += counts[i];
    }
    if (end >= n) offs[n] = part[1023];
}

__global__ void scatter_kernel(const void* __restrict__ ei, int* __restrict__ cursor,
                               int* __restrict__ csr_src, int E, int Etot, int Nn,
                               const int* __restrict__ flags) {
    int i = blockIdx.x * blockDim.x + threadIdx.x;
    if (i >= Etot) return;
    int f64 = flags[1];
    int src, dst;
    if (i < E) {
        src = load_idx(ei, i, f64);
        dst = load_idx(ei, (long long)E + i, f64);
    } else {
        src = dst = i - E;
    }
    src = min(max(src, 0), Nn - 1);
    dst = min(max(dst, 0), Nn - 1);
    int pos = atomicAdd(&cursor[dst], 1);
    csr_src[pos] = src;
}

// ---- MFMA bf16 GEMM + fused alpha logits -----------------------------------
// C[M,Nc] = A[M,K] @ Bt[Nc,K]^T (bf16 out). A block's 64-col tile = one head,
// so alpha_{s,d}[row,head] = sum_col acc*att reduces fully in-wave.
__global__ __launch_bounds__(256) void gemm_bf16(const ushort* __restrict__ A,
                                                 const ushort* __restrict__ Bt,
                                                 ushort* __restrict__ C,
                                                 int M, int K, int Nc,
                                                 const void* __restrict__ aS,
                                                 const void* __restrict__ aD,
                                                 float* __restrict__ alphaS,
                                                 float* __restrict__ alphaD,
                                                 int H, const int* __restrict__ flags) {
    int f = flags[0];
    int tid = threadIdx.x;
    int wave = tid >> 6, lane = tid & 63, quad = lane >> 4, l16 = lane & 15;
    int rbase = blockIdx.x * 256 + wave * 64;
    int cbase = blockIdx.y * 64;
    int head = blockIdx.y;
    floatx4 acc[4][4];
#pragma unroll
    for (int i = 0; i < 4; i++)
#pragma unroll
        for (int j = 0; j < 4; j++) acc[i][j] = (floatx4)0.f;

    for (int kb = 0; kb < K; kb += 32) {
        int k0 = kb + quad * 8;
        short8 a[4], b[4];
#pragma unroll
        for (int mt = 0; mt < 4; mt++) {
            int row = rbase + mt * 16 + l16;
            if (row >= M) row = M - 1;  // clamp; oob rows never stored
            a[mt] = *reinterpret_cast<const short8*>(A + (size_t)row * K + k0);
        }
#pragma unroll
        for (int nt = 0; nt < 4; nt++) {
            int col = cbase + nt * 16 + l16;
            b[nt] = *reinterpret_cast<const short8*>(Bt + (size_t)col * K + k0);
        }
#pragma unroll
        for (int mt = 0; mt < 4; mt++)
#pragma unroll
            for (int nt = 0; nt < 4; nt++)
                acc[mt][nt] = __builtin_amdgcn_mfma_f32_16x16x32_bf16(
                    a[mt], b[nt], acc[mt][nt], 0, 0, 0);
    }
    // attention vectors for this head's 4 col-slots of this lane
    float asv[4], adv[4];
#pragma unroll
    for (int nt = 0; nt < 4; nt++) {
        int col = cbase + nt * 16 + l16;
        asv[nt] = load_in(aS, col, f);
        adv[nt] = load_in(aD, col, f);
    }
    // C/D layout: col = lane&15, row = quad*4 + reg   [m89-verified]
#pragma unroll
    for (int mt = 0; mt < 4; mt++) {
#pragma unroll
        for (int r = 0; r < 4; r++) {
            int row = rbase + mt * 16 + quad * 4 + r;
            float ps = 0.f, pd = 0.f;
#pragma unroll
            for (int nt = 0; nt < 4; nt++) {
                float w = acc[mt][nt][r];
                ps += w * asv[nt];
                pd += w * adv[nt];
            }
#pragma unroll
            for (int off = 8; off > 0; off >>= 1) {  // reduce over 16 col-lanes
                ps += __shfl_xor(ps, off, 16);
                pd += __shfl_xor(pd, off, 16);
            }
            if (row < M) {
                if (l16 == 0) {
                    alphaS[row * H + head] = ps;
                    alphaD[row * H + head] = pd;
                }
#pragma unroll
                for (int nt = 0; nt < 4; nt++) {
                    int col = cbase + nt * 16 + l16;
                    C[(size_t)row * Nc + col] = f2bf(acc[mt][nt][r]);
                }
            }
        }
    }
}

// ---- layer-1 aggregation: 1 wave/node, 8-deep chunked gather pipeline ------
// lane = head(lane>>4) x 4 channels. Direct-sum softmax (|logit| <~ 12).
__global__ __launch_bounds__(256) void gat_node1(const int* __restrict__ csr_src,
                                                 const int* __restrict__ offs,
                                                 const float* __restrict__ asrc,
                                                 const float* __restrict__ adst,
                                                 const ushort* __restrict__ h1b,
                                                 const void* __restrict__ b1,
                                                 ushort* __restrict__ hmidb,
                                                 int Nn, const int* __restrict__ flags) {
    int f = flags[0];
    int wave = threadIdx.x >> 6, lane = threadIdx.x & 63;
    int n = blockIdx.x * 4 + wave;
    if (n >= Nn) return;
    int hh = lane >> 4;
    float ad = adst[n * H1 + hh];
    int beg = offs[n], end = offs[n + 1];
    float acc0 = 0.f, acc1 = 0.f, acc2 = 0.f, acc3 = 0.f, l = 0.f;

    int e = beg;
    while (e + 8 <= end) {
        int sj[8];
#pragma unroll
        for (int j = 0; j < 8; ++j) sj[j] = csr_src[e + j];
        float aj[8]; uint2 vj[8];
#pragma unroll
        for (int j = 0; j < 8; ++j) {
            aj[j] = asrc[sj[j] * H1 + hh];
            vj[j] = *reinterpret_cast<const uint2*>(h1b + (size_t)sj[j] * FIN + lane * 4);
        }
#pragma unroll
        for (int j = 0; j < 8; ++j) {
            float s = aj[j] + ad;
            s = s > 0.f ? s : 0.2f * s;          // leaky_relu 0.2
            float p = __expf(s);
            l += p;
            union { unsigned int i; float fl; } c0, c1, c2, c3;
            c0.i = vj[j].x << 16; c1.i = vj[j].x & 0xffff0000u;
            c2.i = vj[j].y << 16; c3.i = vj[j].y & 0xffff0000u;
            acc0 += p * c0.fl; acc1 += p * c1.fl;
            acc2 += p * c2.fl; acc3 += p * c3.fl;
        }
        e += 8;
    }
    for (; e < end; ++e) {
        int src = csr_src[e];
        float a = asrc[src * H1 + hh];
        uint2 vv = *reinterpret_cast<const uint2*>(h1b + (size_t)src * FIN + lane * 4);
        float s = a + ad;
        s = s > 0.f ? s : 0.2f * s;
        float p = __expf(s);
        l += p;
        union { unsigned int i; float fl; } c0, c1, c2, c3;
        c0.i = vv.x << 16; c1.i = vv.x & 0xffff0000u;
        c2.i = vv.y << 16; c3.i = vv.y & 0xffff0000u;
        acc0 += p * c0.fl; acc1 += p * c1.fl;
        acc2 += p * c2.fl; acc3 += p * c3.fl;
    }
    float inv = 1.f / (l + 1e-16f);
    float o0 = acc0 * inv + load_in(b1, lane * 4 + 0, f);
    float o1 = acc1 * inv + load_in(b1, lane * 4 + 1, f);
    float o2 = acc2 * inv + load_in(b1, lane * 4 + 2, f);
    float o3 = acc3 * inv + load_in(b1, lane * 4 + 3, f);
    o0 = o0 > 0.f ? o0 : __expf(o0) - 1.f;   // ELU
    o1 = o1 > 0.f ? o1 : __expf(o1) - 1.f;
    o2 = o2 > 0.f ? o2 : __expf(o2) - 1.f;
    o3 = o3 > 0.f ? o3 : __expf(o3) - 1.f;
    ushort4 st;
    st.x = f2bf(o0); st.y = f2bf(o1); st.z = f2bf(o2); st.w = f2bf(o3);
    *reinterpret_cast<ushort4*>(hmidb + (size_t)n * FIN + lane * 4) = st;
}

// ---- layer-2 aggregation: 1 wave/node, chunked pipeline, lane = channel ----
__global__ __launch_bounds__(256) void gat_node2(const int* __restrict__ csr_src,
                                                 const int* __restrict__ offs,
                                                 const float* __restrict__ asrc,
                                                 const float* __restrict__ adst,
                                                 const ushort* __restrict__ h2b,
                                                 const void* __restrict__ b2,
                                                 void* __restrict__ out, int Nn,
                                                 const int* __restrict__ flags) {
    int f = flags[0];
    int wave = threadIdx.x >> 6, lane = threadIdx.x & 63;
    int n = blockIdx.x * 4 + wave;
    if (n >= Nn) return;
    float ad = adst[n];
    int beg = offs[n], end = offs[n + 1];
    float acc = 0.f, l = 0.f;

    int e = beg;
    while (e + 8 <= end) {
        int sj[8];
#pragma unroll
        for (int j = 0; j < 8; ++j) sj[j] = csr_src[e + j];
        float aj[8]; ushort vj[8];
#pragma unroll
        for (int j = 0; j < 8; ++j) {
            aj[j] = asrc[sj[j]];
            vj[j] = h2b[(size_t)sj[j] * CH + lane];
        }
#pragma unroll
        for (int j = 0; j < 8; ++j) {
            float s = aj[j] + ad;
            s = s > 0.f ? s : 0.2f * s;
            float p = __expf(s);
            l += p;
            acc += p * bf2f(vj[j]);
        }
        e += 8;
    }
    for (; e < end; ++e) {
        int src = csr_src[e];
        float s = asrc[src] + ad;
        s = s > 0.f ? s : 0.2f * s;
        float p = __expf(s);
        l += p;
        acc += p * bf2f(h2b[(size_t)src * CH + lane]);
    }
    float o = acc / (l + 1e-16f) + load_in(b2, lane, f);
    size_t oi = (size_t)n * CH + lane;
    if (f) ((float*)out)[oi] = o;
    else   ((ushort*)out)[oi] = f2bf(o);
}

extern "C" void kernel_launch(void* const* d_in, const int* in_sizes, int n_in,
                              void* d_out, int out_size, void* d_ws, size_t ws_size,
                              hipStream_t stream) {
    const void* x   = d_in[0];
    const void* ei  = d_in[1];
    const void* W1  = d_in[2];
    const void* as1 = d_in[3];
    const void* ad1 = d_in[4];
    const void* b1  = d_in[5];
    const void* W2  = d_in[6];
    const void* as2 = d_in[7];
    const void* ad2 = d_in[8];
    const void* b2  = d_in[9];

    const int Nn = in_sizes[0] / FIN;      // 50000
    const int E  = in_sizes[1] / 2;        // 1600000
    const int ET = E + Nn;

    char* ws = (char*)d_ws;
    size_t off = 0;
    auto alloc = [&](size_t bytes) {
        size_t o = off;
        off += (bytes + 255) & ~(size_t)255;
        return o;
    };
    ushort* xb    = (ushort*)(ws + alloc((size_t)Nn * FIN * 2));
    ushort* h1b   = (ushort*)(ws + alloc((size_t)Nn * FIN * 2));
    ushort* hmidb = (ushort*)(ws + alloc((size_t)Nn * FIN * 2));
    ushort* h2b   = (ushort*)(ws + alloc((size_t)Nn * CH * 2));
    ushort* Wt1   = (ushort*)(ws + alloc((size_t)FIN * FIN * 2));
    ushort* Wt2   = (ushort*)(ws + alloc((size_t)CH * FIN * 2));
    float* as1f   = (float*)(ws + alloc((size_t)Nn * H1 * 4));
    float* ad1f   = (float*)(ws + alloc((size_t)Nn * H1 * 4));
    float* as2f   = (float*)(ws + alloc((size_t)Nn * 4));
    float* ad2f   = (float*)(ws + alloc((size_t)Nn * 4));
    int*   counts = (int*)(ws + alloc((size_t)Nn * 4));
    int*   offs   = (int*)(ws + alloc((size_t)(Nn + 1) * 4));
    int*   cursor = (int*)(ws + alloc((size_t)Nn * 4));
    int*   csr    = (int*)(ws + alloc((size_t)ET * 4));
    int*   flags  = (int*)(ws + alloc(256));
    (void)ws_size; (void)n_in; (void)out_size;

    probe_kernel<<<1, 256, 0, stream>>>((const ushort*)x, (const int*)ei, flags);
    hipMemsetAsync(counts, 0, (size_t)Nn * 4, stream);

    int prep_total = Nn * FIN + FIN * FIN + CH * FIN;
    prep_kernel<<<(prep_total + 255) / 256, 256, 0, stream>>>(
        x, W1, W2, xb, Wt1, Wt2, Nn * FIN, flags);

    int eb = (ET + 255) / 256;
    hist_kernel<<<eb, 256, 0, stream>>>(ei, counts, E, ET, Nn, flags);
    scan_kernel<<<1, 1024, 0, stream>>>(counts, offs, cursor, Nn);
    scatter_kernel<<<eb, 256, 0, stream>>>(ei, cursor, csr, E, ET, Nn, flags);

    // layer 1 (alpha fused into GEMM epilogue)
    gemm_bf16<<<dim3((Nn + 255) / 256, FIN / 64), 256, 0, stream>>>(
        xb, Wt1, h1b, Nn, FIN, FIN, as1, ad1, as1f, ad1f, H1, flags);
    gat_node1<<<(Nn + 3) / 4, 256, 0, stream>>>(csr, offs, as1f, ad1f, h1b, b1, hmidb, Nn, flags);

    // layer 2
    gemm_bf16<<<dim3((Nn + 255) / 256, CH / 64), 256, 0, stream>>>(
        hmidb, Wt2, h2b, Nn, FIN, CH, as2, ad2, as2f, ad2f, 1, flags);
    gat_node2<<<(Nn + 3) / 4, 256, 0, stream>>>(csr, offs, as2f, ad2f, h2b, b2, d_out, Nn, flags);
}